// Round 8
// baseline (366.965 us; speedup 1.0000x reference)
//
#include <hip/hip_runtime.h>
#include <stdint.h>
#include <math.h>

typedef _Float16 half8_t __attribute__((ext_vector_type(8)));
typedef float floatx4 __attribute__((ext_vector_type(4)));

#define NN 20000
#define NE 40000
#define NG 1000
#define NBLK 313      // (NE+127)/128
#define NSPLIT 4

// ---- fused prep: [blocks 0..2499] x0->e16 pad + root0 ; [2500..] w2 -> B-frag images ----
__global__ __launch_bounds__(256) void prep_fused_kernel(
    const float* __restrict__ x, const float* __restrict__ root0,
    const float* __restrict__ bias0, _Float16* __restrict__ e16, float* __restrict__ xn0,
    const float* __restrict__ w2a, const float* __restrict__ b2a, _Float16* __restrict__ oa,
    const float* __restrict__ w2b, const float* __restrict__ b2b, _Float16* __restrict__ ob,
    const float* __restrict__ w2c, const float* __restrict__ b2c, _Float16* __restrict__ oc)
{
  if (blockIdx.x < 2500) {
    __shared__ float xs[8 * 13];
    int n0 = blockIdx.x * 8;
    int t = threadIdx.x;
    if (t < 104) xs[t] = x[(size_t)n0 * 13 + t];
    __syncthreads();
    if (t < 128) {
      int r = t >> 4, i = t & 15;
      e16[(size_t)(n0 + r) * 16 + i] = (i < 13) ? (_Float16)xs[r * 13 + i] : (_Float16)0.f;
    }
    int r = t >> 5, o = t & 31;
    float acc = bias0[o];
#pragma unroll
    for (int i = 0; i < 13; ++i) acc = fmaf(xs[r * 13 + i], root0[i * 32 + o], acc);
    xn0[(size_t)(n0 + r) * 32 + o] = acc;
    return;
  }
  const int TOT0 = 68 * 2 * 64, TOT1 = 132 * 4 * 64, TOT2 = 264 * 4 * 64;
  int idx = (blockIdx.x - 2500) * 256 + threadIdx.x;
  const float *w2, *b2; _Float16* op; int mi, mo, mpsh, CT;
  if (idx < TOT0) { w2 = w2a; b2 = b2a; op = oa; mi = 13; mo = 32; mpsh = 4; CT = 2; }
  else if (idx < TOT0 + TOT1) { idx -= TOT0; w2 = w2b; b2 = b2b; op = ob; mi = 32; mo = 64; mpsh = 5; CT = 4; }
  else if (idx < TOT0 + TOT1 + TOT2) { idx -= TOT0 + TOT1; w2 = w2c; b2 = b2c; op = oc; mi = 64; mo = 64; mpsh = 6; CT = 4; }
  else return;
  int l = idx & 63;
  int ct = (idx >> 6) % CT;
  int c = idx / (64 * CT);
  int q = l >> 4;
  int n = ct * 16 + (l & 15);
  int mask = (1 << mpsh) - 1;
  half8_t v;
#pragma unroll
  for (int j = 0; j < 8; ++j) {
    int r = c * 32 + q * 8 + j;
    int k = r >> mpsh, i = r & mask;
    float f = 0.f;
    if (i < mi) {
      if (k < 128) f = w2[(size_t)(k * mi + i) * mo + n];
      else if (k == 128) f = b2[(size_t)i * mo + n];
    }
    v[j] = (_Float16)f;
  }
  *(half8_t*)(op + (size_t)idx * 8) = v;
}

// ---- fused: elu(prev conv out) -> e16 for msg, and xnext = elu(x)@root + bias ----
template <int MI, int MOX>
__global__ __launch_bounds__(256) void elu_root_kernel(
    const float* __restrict__ xin, const float* __restrict__ root,
    const float* __restrict__ bias, _Float16* __restrict__ e16,
    float* __restrict__ xnext)
{
  constexpr int R = 256 / MOX;   // 4 rows/block
  __shared__ float es[R * MI];
  int n0 = blockIdx.x * R;
  int t = threadIdx.x;
  for (int idx = t; idx < R * MI; idx += 256) {
    float v = xin[(size_t)n0 * MI + idx];
    v = v > 0.f ? v : (expf(v) - 1.f);
    es[idx] = v;
    e16[(size_t)n0 * MI + idx] = (_Float16)v;
  }
  __syncthreads();
  int r = t / MOX, o = t % MOX;
  float acc = bias[o];
#pragma unroll 8
  for (int i = 0; i < MI; ++i) acc = fmaf(es[r * MI + i], root[i * MOX + o], acc);
  xnext[(size_t)(n0 + r) * MOX + o] = acc;
}

// ---------------- fused h-MLP + message GEMM + scatter-add ----------------
// C[E,MO] = G[E,Kpad] @ W ; G[e][k*MIP+i] = h[e][k]*x[e][i] (fp16), h[.][128]=1 carries b2.
// Block = 128 edges, 4 waves, wave = M32 x N=MO. NEW: h values preloaded into registers
// (hpk[j] packs s0|s1 rows per k) -> K-loop has NO LDS h reads; W LDS-dbuf with depth-2
// global prefetch; K-loop FULLY UNROLLED (NCC constexpr) so all reg indices are literals.
// KREG = distinct k per split per lane; KSTORE = h values stored per split.
template <int MIP, int MO, int NCC, int KREG, int KSTORE>
__global__ __launch_bounds__(256, 3) void msg8_kernel(
    const float* __restrict__ ea, const float* __restrict__ w1,
    const float* __restrict__ b1, const _Float16* __restrict__ xe,
    const int* __restrict__ src, const int* __restrict__ dst,
    const _Float16* __restrict__ w2h, float* __restrict__ xn)
{
  constexpr int CT = MO / 16;             // 16-col tiles (full N per wave)
  constexpr int CHB = CT * 1024;          // bytes per W chunk image
  constexpr int XLSS = MIP + 8;           // x staging row stride (halves)
  constexpr int HST = KSTORE | 1;         // h row stride (ushorts)
  constexpr int XV = (MIP == 64) ? 2 : 1;
  constexpr int NU2 = MIP / 16;           // uint4s per x half-row
  constexpr int KH = (KSTORE + 1) >> 1;
  constexpr int XB = 128 * XLSS * 2;
  constexpr int HB = 128 * HST * 2;
  constexpr int SBYTES = (XB > HB) ? XB : HB;

  __shared__ char sb[SBYTES];             // phase A: x rows (fp16); phase B: h rows (u16)
  __shared__ uint4 wsb[2][CHB / 16];      // double-buffered W chunk
  __shared__ float w1s[5 * 128 + 128];    // w1 then b1
  __shared__ int dsts[128];

  _Float16* sxb = (_Float16*)sb;
  unsigned short* hls = (unsigned short*)sb;

  const int t = threadIdx.x;
  const int wave = t >> 6, lane = t & 63;
  const int l15 = lane & 15, q = lane >> 4;
  const int split = blockIdx.x / NBLK;
  const int e0 = (blockIdx.x % NBLK) * 128;
  const int c0 = NCC * split;
  const int kg0 = KSTORE * split;

  // ---- phase A: stage x rows (2 threads/row), w1/b1, dst; edge attrs to regs ----
  {
    int rowA = t >> 1;
    int egA = e0 + rowA; if (egA >= NE) egA = NE - 1;
    const uint4* xr = (const uint4*)(xe + (size_t)src[egA] * MIP);
    uint4* xd = (uint4*)(sxb + rowA * XLSS);
#pragma unroll
    for (int u = 0; u < NU2; ++u) xd[(t & 1) * NU2 + u] = xr[(t & 1) * NU2 + u];
  }
  if (t < 128) {
    int eg = e0 + t; if (eg >= NE) eg = NE - 1;
    dsts[t] = dst[eg];
  }
  const int te = t & 127;
  float ear[5];
  {
    int ege = e0 + te; if (ege >= NE) ege = NE - 1;
#pragma unroll
    for (int j = 0; j < 5; ++j) ear[j] = ea[(size_t)ege * 5 + j];
  }
  for (int i = t; i < 768; i += 256) w1s[i] = (i < 640) ? w1[i] : b1[i - 640];
  __syncthreads();

  // ---- x fragments to registers; start W prefetch (depth 2) ----
  const int wbase = wave * 32;
  half8_t xf[2][XV];
#pragma unroll
  for (int s = 0; s < 2; ++s) {
    int el = wbase + s * 16 + l15;
    int i0 = (MIP == 16) ? (q & 1) * 8 : q * 8;
    xf[s][0] = *(const half8_t*)(sxb + el * XLSS + i0);
    if constexpr (MIP == 64)
      xf[s][XV - 1] = *(const half8_t*)(sxb + el * XLSS + 32 + q * 8);
  }
  const char* wgp = (const char*)w2h + (size_t)c0 * CHB;
  uint4 rr4[2]; uint2 rr2[2];
  if constexpr (CT == 4) {
    rr4[0] = *(const uint4*)(wgp + t * 16);
    rr4[1] = *(const uint4*)(wgp + CHB + t * 16);
  } else {
    rr2[0] = *(const uint2*)(wgp + t * 8);
    rr2[1] = *(const uint2*)(wgp + CHB + t * 8);
  }
  __syncthreads();

  // ---- phase B: h rows (u16) into sb; each edge split across thread halves ----
  {
    int kh = t >> 7;
    int klo = kh * KH;
    int khi = klo + KH; if (khi > KSTORE) khi = KSTORE;
    for (int kl = klo; kl < khi; ++kl) {
      int kg = kg0 + kl;
      float v;
      if (kg < 128) {
        v = w1s[640 + kg];
#pragma unroll
        for (int j = 0; j < 5; ++j) v = fmaf(ear[j], w1s[j * 128 + kg], v);
        v = fmaxf(v, 0.f);
      } else v = (kg == 128) ? 1.f : 0.f;
      union { _Float16 f; unsigned short u; } cv; cv.f = (_Float16)v;
      hls[te * HST + kl] = cv.u;
    }
  }
  __syncthreads();

  // ---- h values to registers: hpk[j] = h[row_s0,kj] | h[row_s1,kj]<<16 ----
  unsigned hpk[KREG];
#pragma unroll
  for (int j = 0; j < KREG; ++j) {
    int kl = (MIP == 16) ? (2 * j + (q >> 1)) : j;
    unsigned lo = hls[(wbase + l15) * HST + kl];
    unsigned hi = hls[(wbase + 16 + l15) * HST + kl];
    hpk[j] = lo | (hi << 16);
  }

  // ---- K loop: fully unrolled, LDS-dbuf W, reg h, depth-2 prefetch ----
  floatx4 acc[2][CT];
#pragma unroll
  for (int s = 0; s < 2; ++s)
#pragma unroll
    for (int b = 0; b < CT; ++b) acc[s][b] = (floatx4){0.f, 0.f, 0.f, 0.f};

#pragma unroll
  for (int cc = 0; cc < NCC; ++cc) {
    if constexpr (CT == 4) wsb[cc & 1][t] = rr4[cc & 1];
    else ((uint2*)wsb[cc & 1])[t] = rr2[cc & 1];
    __syncthreads();
    {
      int cp = (cc + 2 < NCC) ? (cc + 2) : cc;   // folds per unrolled iter
      if constexpr (CT == 4) rr4[cc & 1] = *(const uint4*)(wgp + (size_t)cp * CHB + t * 16);
      else rr2[cc & 1] = *(const uint2*)(wgp + (size_t)cp * CHB + t * 8);
    }
    const _Float16* wb = (const _Float16*)wsb[cc & 1];
    half8_t bf[CT];
#pragma unroll
    for (int b = 0; b < CT; ++b)
      bf[b] = *(const half8_t*)(wb + (b * 64 + lane) * 8);

    const int KI = (MIP == 64) ? (cc >> 1) : cc;  // literal after unroll
    union { unsigned u; _Float16 f[2]; } uu; uu.u = hpk[KI];
    half8_t af0, af1;
    if constexpr (MIP == 64) {
      af0 = xf[0][cc & 1] * uu.f[0];
      af1 = xf[1][cc & 1] * uu.f[1];
    } else {
      af0 = xf[0][0] * uu.f[0];
      af1 = xf[1][0] * uu.f[1];
    }
#pragma unroll
    for (int b = 0; b < CT; ++b) {
      acc[0][b] = __builtin_amdgcn_mfma_f32_16x16x32_f16(af0, bf[b], acc[0][b], 0, 0, 0);
      acc[1][b] = __builtin_amdgcn_mfma_f32_16x16x32_f16(af1, bf[b], acc[1][b], 0, 0, 0);
    }
  }

  // ---- epilogue: D row = 4q+r (within 16-tile), col = l15; scatter-add ----
#pragma unroll
  for (int s = 0; s < 2; ++s) {
    int rowb = wbase + s * 16 + q * 4;
#pragma unroll
    for (int b = 0; b < CT; ++b) {
      int n = b * 16 + l15;
#pragma unroll
      for (int r = 0; r < 4; ++r) {
        int row = rowb + r;
        if (e0 + row < NE)
          atomicAdd(&xn[(size_t)dsts[row] * MO + n], acc[s][b][r]);
      }
    }
  }
}

// ---- pooling (segment mean over sorted batch, fused ELU) + 3-layer FC head ----
__global__ __launch_bounds__(64) void pool_fc_kernel(
    const float* __restrict__ xn2, const int* __restrict__ batch,
    const float* __restrict__ f1w, const float* __restrict__ f1b,
    const float* __restrict__ f2w, const float* __restrict__ f2b,
    const float* __restrict__ f3w, const float* __restrict__ f3b,
    float* __restrict__ out)
{
  __shared__ float xg[64]; __shared__ float a1[32]; __shared__ float a2[16];
  int g = blockIdx.x, t = threadIdx.x;
  int lo = 0, hi = NN;
  while (lo < hi) { int m = (lo + hi) >> 1; if (batch[m] < g) lo = m + 1; else hi = m; }
  int start = lo; hi = NN;
  while (lo < hi) { int m = (lo + hi) >> 1; if (batch[m] <= g) lo = m + 1; else hi = m; }
  int end = lo;
  float acc = 0.f;
  for (int n = start; n < end; ++n) {
    float v = xn2[(size_t)n * 64 + t];
    acc += v > 0.f ? v : (expf(v) - 1.f);
  }
  float c = (end > start) ? (float)(end - start) : 1.f;
  xg[t] = acc / c;
  __syncthreads();
  if (t < 32) {
    float a = f1b[t];
    for (int i = 0; i < 64; ++i) a = fmaf(xg[i], f1w[i * 32 + t], a);
    a1[t] = a > 0.f ? a : (expf(a) - 1.f);
  }
  __syncthreads();
  if (t < 16) {
    float a = f2b[t];
    for (int i = 0; i < 32; ++i) a = fmaf(a1[i], f2w[i * 16 + t], a);
    a2[t] = a > 0.f ? a : (expf(a) - 1.f);
  }
  __syncthreads();
  if (t == 0) {
    float a = f3b[0];
    for (int i = 0; i < 16; ++i) a = fmaf(a2[i], f3w[i], a);
    out[g] = a;
  }
}

extern "C" void kernel_launch(void* const* d_in, const int* in_sizes, int n_in,
                              void* d_out, int out_size, void* d_ws, size_t ws_size,
                              hipStream_t stream)
{
  const float* x_in  = (const float*)d_in[0];
  const int*   ei    = (const int*)d_in[1];
  const float* ea    = (const float*)d_in[2];
  const int*   batch = (const int*)d_in[3];
  const float* W1[3] = {(const float*)d_in[4],  (const float*)d_in[10], (const float*)d_in[16]};
  const float* B1[3] = {(const float*)d_in[5],  (const float*)d_in[11], (const float*)d_in[17]};
  const float* W2[3] = {(const float*)d_in[6],  (const float*)d_in[12], (const float*)d_in[18]};
  const float* B2[3] = {(const float*)d_in[7],  (const float*)d_in[13], (const float*)d_in[19]};
  const float* RT[3] = {(const float*)d_in[8],  (const float*)d_in[14], (const float*)d_in[20]};
  const float* BS[3] = {(const float*)d_in[9],  (const float*)d_in[15], (const float*)d_in[21]};
  const float* f1w = (const float*)d_in[22]; const float* f1b = (const float*)d_in[23];
  const float* f2w = (const float*)d_in[24]; const float* f2b = (const float*)d_in[25];
  const float* f3w = (const float*)d_in[26]; const float* f3b = (const float*)d_in[27];

  char* ws = (char*)d_ws;
  size_t off = 0;
  auto alloc = [&](size_t bytes) { void* p = ws + off; off += (bytes + 255) & ~(size_t)255; return p; };
  float*    xn0   = (float*)alloc((size_t)NN * 32 * 4);
  float*    xn1   = (float*)alloc((size_t)NN * 64 * 4);
  float*    xn2   = (float*)alloc((size_t)NN * 64 * 4);
  _Float16* e16_0 = (_Float16*)alloc((size_t)NN * 16 * 2);
  _Float16* e16_1 = (_Float16*)alloc((size_t)NN * 32 * 2);
  _Float16* e16_2 = (_Float16*)alloc((size_t)NN * 64 * 2);
  _Float16* w2h0  = (_Float16*)alloc((size_t)68 * 2048);
  _Float16* w2h1  = (_Float16*)alloc((size_t)132 * 4096);
  _Float16* w2h2  = (_Float16*)alloc((size_t)264 * 4096);

  const int* srcp = ei;
  const int* dstp = ei + NE;

  const int PREPB = 2500 + (68*2*64 + 132*4*64 + 264*4*64 + 255) / 256;
  prep_fused_kernel<<<PREPB, 256, 0, stream>>>(
      x_in, RT[0], BS[0], e16_0, xn0,
      W2[0], B2[0], w2h0, W2[1], B2[1], w2h1, W2[2], B2[2], w2h2);

  msg8_kernel<16, 32, 17, 17, 34><<<NBLK * NSPLIT, 256, 0, stream>>>(
      ea, W1[0], B1[0], e16_0, srcp, dstp, w2h0, xn0);
  elu_root_kernel<32, 64><<<NN / 4, 256, 0, stream>>>(xn0, RT[1], BS[1], e16_1, xn1);

  msg8_kernel<32, 64, 33, 33, 33><<<NBLK * NSPLIT, 256, 0, stream>>>(
      ea, W1[1], B1[1], e16_1, srcp, dstp, w2h1, xn1);
  elu_root_kernel<64, 64><<<NN / 4, 256, 0, stream>>>(xn1, RT[2], BS[2], e16_2, xn2);

  msg8_kernel<64, 64, 66, 33, 33><<<NBLK * NSPLIT, 256, 0, stream>>>(
      ea, W1[2], B1[2], e16_2, srcp, dstp, w2h2, xn2);

  pool_fc_kernel<<<NG, 64, 0, stream>>>(xn2, batch, f1w, f1b, f2w, f2b, f3w, f3b, (float*)d_out);
}

// Round 9
// 333.041 us; speedup vs baseline: 1.1019x; 1.1019x over previous
//
#include <hip/hip_runtime.h>
#include <stdint.h>
#include <math.h>

typedef _Float16 half8_t __attribute__((ext_vector_type(8)));
typedef float floatx4 __attribute__((ext_vector_type(4)));

#define NN 20000
#define NE 40000
#define NG 1000
#define NBLK 313      // (NE+127)/128
#define NSPLIT 4

// ---- fused prep: [0,1250) x0->e16 pad ; [1250,1680) w2 -> B-frag images ; [1680..) deg=0 ----
__global__ __launch_bounds__(256) void prep_fused_kernel(
    const float* __restrict__ x, _Float16* __restrict__ e16,
    const float* __restrict__ w2a, const float* __restrict__ b2a, _Float16* __restrict__ oa,
    const float* __restrict__ w2b, const float* __restrict__ b2b, _Float16* __restrict__ ob,
    const float* __restrict__ w2c, const float* __restrict__ b2c, _Float16* __restrict__ oc,
    int* __restrict__ deg)
{
  if (blockIdx.x < 1250) {
    int idx = blockIdx.x * 256 + threadIdx.x;   // over NN*16
    int n = idx >> 4, i = idx & 15;
    e16[idx] = (i < 13) ? (_Float16)x[(size_t)n * 13 + i] : (_Float16)0.f;
    return;
  }
  if (blockIdx.x >= 1680) {
    int n = (blockIdx.x - 1680) * 256 + threadIdx.x;
    if (n < NN) deg[n] = 0;
    return;
  }
  const int TOT0 = 68 * 2 * 64, TOT1 = 132 * 4 * 64, TOT2 = 264 * 4 * 64;
  int idx = (blockIdx.x - 1250) * 256 + threadIdx.x;
  const float *w2, *b2; _Float16* op; int mi, mo, mpsh, CT;
  if (idx < TOT0) { w2 = w2a; b2 = b2a; op = oa; mi = 13; mo = 32; mpsh = 4; CT = 2; }
  else if (idx < TOT0 + TOT1) { idx -= TOT0; w2 = w2b; b2 = b2b; op = ob; mi = 32; mo = 64; mpsh = 5; CT = 4; }
  else if (idx < TOT0 + TOT1 + TOT2) { idx -= TOT0 + TOT1; w2 = w2c; b2 = b2c; op = oc; mi = 64; mo = 64; mpsh = 6; CT = 4; }
  else return;
  int l = idx & 63;
  int ct = (idx >> 6) % CT;
  int c = idx / (64 * CT);
  int q = l >> 4;
  int n = ct * 16 + (l & 15);
  int mask = (1 << mpsh) - 1;
  half8_t v;
#pragma unroll
  for (int j = 0; j < 8; ++j) {
    int r = c * 32 + q * 8 + j;
    int k = r >> mpsh, i = r & mask;
    float f = 0.f;
    if (i < mi) {
      if (k < 128) f = w2[(size_t)(k * mi + i) * mo + n];
      else if (k == 128) f = b2[(size_t)i * mo + n];
    }
    v[j] = (_Float16)f;
  }
  *(half8_t*)(op + (size_t)idx * 8) = v;
}

// ---- CSR build: histogram, scan, fill ----
__global__ __launch_bounds__(256) void deg_kernel(const int* __restrict__ dst, int* __restrict__ deg) {
  int e = blockIdx.x * 256 + threadIdx.x;
  if (e < NE) atomicAdd(&deg[dst[e]], 1);
}

__global__ __launch_bounds__(256) void scan_kernel(
    const int* __restrict__ deg, int* __restrict__ row_ptr, int* __restrict__ cursor)
{
  __shared__ int ps[256];
  int t = threadIdx.x;
  const int CH = (NN + 255) / 256;   // 79
  int base = t * CH;
  int s = 0;
  for (int i = 0; i < CH; ++i) { int n = base + i; if (n < NN) s += deg[n]; }
  ps[t] = s;
  __syncthreads();
  if (t == 0) { int run = 0; for (int i = 0; i < 256; ++i) { int v = ps[i]; ps[i] = run; run += v; } }
  __syncthreads();
  int run = ps[t];
  for (int i = 0; i < CH; ++i) {
    int n = base + i;
    if (n < NN) { row_ptr[n] = run; cursor[n] = run; run += deg[n]; }
    else if (n == NN) row_ptr[NN] = run;
  }
}

__global__ __launch_bounds__(256) void fill_kernel(
    const int* __restrict__ dst, int* __restrict__ cursor, int* __restrict__ eids)
{
  int e = blockIdx.x * 256 + threadIdx.x;
  if (e < NE) { int p = atomicAdd(&cursor[dst[e]], 1); eids[p] = e; }
}

// ---------------- fused h-MLP + message GEMM, partial-store epilogue (NO atomics) ----------------
// Identical K-loop/prologue to R7's msg7 (the best measured); epilogue stores fp16 partials to
// msgp[split][e][col] — aggregation moved to gather_kernel.
template <int MIP, int MO, int NCC, int KCNT>
__global__ __launch_bounds__(256, 4) void msg9_kernel(
    const float* __restrict__ ea, const float* __restrict__ w1,
    const float* __restrict__ b1, const _Float16* __restrict__ xe,
    const int* __restrict__ src,
    const _Float16* __restrict__ w2h, _Float16* __restrict__ msgp)
{
  constexpr int CT = MO / 16;
  constexpr int CHB = CT * 1024;
  constexpr int XLSS = MIP + 8;
  constexpr int HSTW = KCNT | 1;          // h row stride in words (odd -> conflict-free)
  constexpr int XV = (MIP == 64) ? 2 : 1;
  constexpr int NU2 = MIP / 16;
  constexpr int KH = (KCNT + 1) >> 1;
  constexpr int XB = 128 * XLSS * 2;
  constexpr int HB = 128 * HSTW * 4;
  constexpr int SBYTES = (XB > HB) ? XB : HB;

  __shared__ char sb[SBYTES];
  __shared__ uint4 wsb[2][CHB / 16];
  __shared__ float w1s[5 * 128 + 128];

  _Float16* sxb = (_Float16*)sb;
  unsigned* hls = (unsigned*)sb;

  const int t = threadIdx.x;
  const int wave = t >> 6, lane = t & 63;
  const int l15 = lane & 15, q = lane >> 4;
  const int split = blockIdx.x / NBLK;
  const int e0 = (blockIdx.x % NBLK) * 128;
  const int c0 = NCC * split;
  const int kg0 = KCNT * split;

  // ---- phase A: stage x rows (2 threads/row), w1/b1; edge attrs to regs ----
  {
    int rowA = t >> 1;
    int egA = e0 + rowA; if (egA >= NE) egA = NE - 1;
    const uint4* xr = (const uint4*)(xe + (size_t)src[egA] * MIP);
    uint4* xd = (uint4*)(sxb + rowA * XLSS);
#pragma unroll
    for (int u = 0; u < NU2; ++u) xd[(t & 1) * NU2 + u] = xr[(t & 1) * NU2 + u];
  }
  const int te = t & 127;
  float ear[5];
  {
    int ege = e0 + te; if (ege >= NE) ege = NE - 1;
#pragma unroll
    for (int j = 0; j < 5; ++j) ear[j] = ea[(size_t)ege * 5 + j];
  }
  for (int i = t; i < 768; i += 256) w1s[i] = (i < 640) ? w1[i] : b1[i - 640];
  __syncthreads();

  // ---- x fragments to registers (2 M-subtiles per wave) ----
  const int wbase = wave * 32;
  half8_t xf[2][XV];
#pragma unroll
  for (int s = 0; s < 2; ++s) {
    int el = wbase + s * 16 + l15;
    int i0 = (MIP == 16) ? (q & 1) * 8 : q * 8;
    xf[s][0] = *(const half8_t*)(sxb + el * XLSS + i0);
    if constexpr (MIP == 64)
      xf[s][XV - 1] = *(const half8_t*)(sxb + el * XLSS + 32 + q * 8);
  }
  __syncthreads();

  // ---- phase B: h rows (packed-dup uint), each edge split across thread halves ----
  {
    int kh = t >> 7;
    int klo = kh * KH;
    int khi = klo + KH; if (khi > KCNT) khi = KCNT;
    for (int kl = klo; kl < khi; ++kl) {
      int kg = kg0 + kl;
      float v;
      if (kg < 128) {
        v = w1s[640 + kg];
#pragma unroll
        for (int j = 0; j < 5; ++j) v = fmaf(ear[j], w1s[j * 128 + kg], v);
        v = fmaxf(v, 0.f);
      } else v = (kg == 128) ? 1.f : 0.f;
      union { _Float16 f; unsigned short u; } cv; cv.f = (_Float16)v;
      hls[te * HSTW + kl] = (unsigned)cv.u * 0x10001u;
    }
  }
  __syncthreads();

  // ---- K loop: 1 barrier/chunk, double-buffered LDS W, all reg indices static ----
  floatx4 acc[2][CT];
#pragma unroll
  for (int s = 0; s < 2; ++s)
#pragma unroll
    for (int b = 0; b < CT; ++b) acc[s][b] = (floatx4){0.f, 0.f, 0.f, 0.f};

  const char* wgp = (const char*)w2h + (size_t)c0 * CHB;
  uint4 r4; uint2 r2;
  if constexpr (CT == 4) r4 = *(const uint4*)(wgp + t * 16);
  else r2 = *(const uint2*)(wgp + t * 8);

#pragma unroll 2
  for (int cc = 0; cc < NCC; ++cc) {
    if constexpr (CT == 4) wsb[cc & 1][t] = r4;
    else ((uint2*)wsb[cc & 1])[t] = r2;
    __syncthreads();
    if (cc + 1 < NCC) {
      if constexpr (CT == 4) r4 = *(const uint4*)(wgp + (size_t)(cc + 1) * CHB + t * 16);
      else r2 = *(const uint2*)(wgp + (size_t)(cc + 1) * CHB + t * 8);
    }
    const _Float16* wb = (const _Float16*)wsb[cc & 1];
    half8_t bf[CT];
#pragma unroll
    for (int b = 0; b < CT; ++b)
      bf[b] = *(const half8_t*)(wb + (b * 64 + lane) * 8);
    int kl;
    if constexpr (MIP == 64) kl = cc >> 1;
    else if constexpr (MIP == 32) kl = cc;
    else kl = 2 * cc + (q >> 1);
#pragma unroll
    for (int s = 0; s < 2; ++s) {
      _Float16 hv = *(const _Float16*)(hls + (wbase + s * 16 + l15) * HSTW + kl);
      half8_t af;
      if constexpr (MIP == 64) af = xf[s][cc & 1] * hv;
      else af = xf[s][0] * hv;
#pragma unroll
      for (int b = 0; b < CT; ++b)
        acc[s][b] = __builtin_amdgcn_mfma_f32_16x16x32_f16(af, bf[b], acc[s][b], 0, 0, 0);
    }
  }

  // ---- epilogue: plain fp16 partial stores, no atomics ----
  _Float16* mp = msgp + (size_t)split * NE * MO;
#pragma unroll
  for (int s = 0; s < 2; ++s) {
    int rowb = wbase + s * 16 + q * 4;
#pragma unroll
    for (int b = 0; b < CT; ++b) {
      int n = b * 16 + l15;
#pragma unroll
      for (int r = 0; r < 4; ++r) {
        int row = rowb + r;
        int e = e0 + row;
        if (e < NE) mp[(size_t)e * MO + n] = (_Float16)acc[s][b][r];
      }
    }
  }
}

// ---- gather: per node, sum CSR-listed edge partials (+root-GEMM +bias), ELU unless FINAL ----
template <int MIN_, int XST, int MO, int FINAL>
__global__ __launch_bounds__(256) void gather_kernel(
    const _Float16* __restrict__ e16in, const float* __restrict__ root,
    const float* __restrict__ bias, const int* __restrict__ row_ptr,
    const int* __restrict__ eids, const _Float16* __restrict__ msgp,
    _Float16* __restrict__ oute, float* __restrict__ outf)
{
  constexpr int NPB = 256 / MO;
  int n = blockIdx.x * NPB + threadIdx.x / MO;
  int o = threadIdx.x % MO;
  if (n >= NN) return;
  float a = bias[o];
#pragma unroll
  for (int i = 0; i < MIN_; ++i)
    a = fmaf((float)e16in[(size_t)n * XST + i], root[i * MO + o], a);
  int r0 = row_ptr[n], r1 = row_ptr[n + 1];
  for (int j = r0; j < r1; ++j) {
    int e = eids[j];
#pragma unroll
    for (int s = 0; s < NSPLIT; ++s)
      a += (float)msgp[((size_t)s * NE + e) * MO + o];
  }
  if constexpr (FINAL) {
    outf[(size_t)n * MO + o] = a;
  } else {
    float v = a > 0.f ? a : (expf(a) - 1.f);
    oute[(size_t)n * MO + o] = (_Float16)v;
  }
}

// ---- pooling (segment mean over sorted batch, fused ELU) + 3-layer FC head ----
__global__ __launch_bounds__(64) void pool_fc_kernel(
    const float* __restrict__ xn2, const int* __restrict__ batch,
    const float* __restrict__ f1w, const float* __restrict__ f1b,
    const float* __restrict__ f2w, const float* __restrict__ f2b,
    const float* __restrict__ f3w, const float* __restrict__ f3b,
    float* __restrict__ out)
{
  __shared__ float xg[64]; __shared__ float a1[32]; __shared__ float a2[16];
  int g = blockIdx.x, t = threadIdx.x;
  int lo = 0, hi = NN;
  while (lo < hi) { int m = (lo + hi) >> 1; if (batch[m] < g) lo = m + 1; else hi = m; }
  int start = lo; hi = NN;
  while (lo < hi) { int m = (lo + hi) >> 1; if (batch[m] <= g) lo = m + 1; else hi = m; }
  int end = lo;
  float acc = 0.f;
  for (int n = start; n < end; ++n) {
    float v = xn2[(size_t)n * 64 + t];
    acc += v > 0.f ? v : (expf(v) - 1.f);
  }
  float c = (end > start) ? (float)(end - start) : 1.f;
  xg[t] = acc / c;
  __syncthreads();
  if (t < 32) {
    float a = f1b[t];
    for (int i = 0; i < 64; ++i) a = fmaf(xg[i], f1w[i * 32 + t], a);
    a1[t] = a > 0.f ? a : (expf(a) - 1.f);
  }
  __syncthreads();
  if (t < 16) {
    float a = f2b[t];
    for (int i = 0; i < 32; ++i) a = fmaf(a1[i], f2w[i * 16 + t], a);
    a2[t] = a > 0.f ? a : (expf(a) - 1.f);
  }
  __syncthreads();
  if (t == 0) {
    float a = f3b[0];
    for (int i = 0; i < 16; ++i) a = fmaf(a2[i], f3w[i], a);
    out[g] = a;
  }
}

extern "C" void kernel_launch(void* const* d_in, const int* in_sizes, int n_in,
                              void* d_out, int out_size, void* d_ws, size_t ws_size,
                              hipStream_t stream)
{
  const float* x_in  = (const float*)d_in[0];
  const int*   ei    = (const int*)d_in[1];
  const float* ea    = (const float*)d_in[2];
  const int*   batch = (const int*)d_in[3];
  const float* W1[3] = {(const float*)d_in[4],  (const float*)d_in[10], (const float*)d_in[16]};
  const float* B1[3] = {(const float*)d_in[5],  (const float*)d_in[11], (const float*)d_in[17]};
  const float* W2[3] = {(const float*)d_in[6],  (const float*)d_in[12], (const float*)d_in[18]};
  const float* B2[3] = {(const float*)d_in[7],  (const float*)d_in[13], (const float*)d_in[19]};
  const float* RT[3] = {(const float*)d_in[8],  (const float*)d_in[14], (const float*)d_in[20]};
  const float* BS[3] = {(const float*)d_in[9],  (const float*)d_in[15], (const float*)d_in[21]};
  const float* f1w = (const float*)d_in[22]; const float* f1b = (const float*)d_in[23];
  const float* f2w = (const float*)d_in[24]; const float* f2b = (const float*)d_in[25];
  const float* f3w = (const float*)d_in[26]; const float* f3b = (const float*)d_in[27];

  char* ws = (char*)d_ws;
  size_t off = 0;
  auto alloc = [&](size_t bytes) { void* p = ws + off; off += (bytes + 255) & ~(size_t)255; return p; };
  float*    xn2   = (float*)alloc((size_t)NN * 64 * 4);
  _Float16* e16_0 = (_Float16*)alloc((size_t)NN * 16 * 2);
  _Float16* e16_1 = (_Float16*)alloc((size_t)NN * 32 * 2);
  _Float16* e16_2 = (_Float16*)alloc((size_t)NN * 64 * 2);
  _Float16* w2h0  = (_Float16*)alloc((size_t)68 * 2048);
  _Float16* w2h1  = (_Float16*)alloc((size_t)132 * 4096);
  _Float16* w2h2  = (_Float16*)alloc((size_t)264 * 4096);
  _Float16* msgp  = (_Float16*)alloc((size_t)NSPLIT * NE * 64 * 2);
  int*      deg     = (int*)alloc((size_t)NN * 4);
  int*      row_ptr = (int*)alloc((size_t)(NN + 1) * 4);
  int*      cursor  = (int*)alloc((size_t)NN * 4);
  int*      eids    = (int*)alloc((size_t)NE * 4);

  const int* srcp = ei;
  const int* dstp = ei + NE;

  prep_fused_kernel<<<1680 + (NN + 255) / 256, 256, 0, stream>>>(
      x_in, e16_0, W2[0], B2[0], w2h0, W2[1], B2[1], w2h1, W2[2], B2[2], w2h2, deg);
  deg_kernel<<<(NE + 255) / 256, 256, 0, stream>>>(dstp, deg);
  scan_kernel<<<1, 256, 0, stream>>>(deg, row_ptr, cursor);
  fill_kernel<<<(NE + 255) / 256, 256, 0, stream>>>(dstp, cursor, eids);

  // ---- layer 0 ----
  msg9_kernel<16, 32, 17, 34><<<NBLK * NSPLIT, 256, 0, stream>>>(
      ea, W1[0], B1[0], e16_0, srcp, w2h0, msgp);
  gather_kernel<13, 16, 32, 0><<<(NN + 7) / 8, 256, 0, stream>>>(
      e16_0, RT[0], BS[0], row_ptr, eids, msgp, e16_1, xn2);

  // ---- layer 1 ----
  msg9_kernel<32, 64, 33, 33><<<NBLK * NSPLIT, 256, 0, stream>>>(
      ea, W1[1], B1[1], e16_1, srcp, w2h1, msgp);
  gather_kernel<32, 32, 64, 0><<<(NN + 3) / 4, 256, 0, stream>>>(
      e16_1, RT[1], BS[1], row_ptr, eids, msgp, e16_2, xn2);

  // ---- layer 2 ----
  msg9_kernel<64, 64, 66, 33><<<NBLK * NSPLIT, 256, 0, stream>>>(
      ea, W1[2], B1[2], e16_2, srcp, w2h2, msgp);
  gather_kernel<64, 64, 64, 1><<<(NN + 3) / 4, 256, 0, stream>>>(
      e16_2, RT[2], BS[2], row_ptr, eids, msgp, e16_2, xn2);

  pool_fc_kernel<<<NG, 64, 0, stream>>>(xn2, batch, f1w, f1b, f2w, f2b, f3w, f3b, (float*)d_out);
}

// Round 10
// 299.916 us; speedup vs baseline: 1.2236x; 1.1104x over previous
//
#include <hip/hip_runtime.h>
#include <stdint.h>
#include <math.h>

typedef _Float16 half8_t __attribute__((ext_vector_type(8)));
typedef float floatx4 __attribute__((ext_vector_type(4)));

#define NN 20000
#define NE 40000
#define NG 1000
#define NBLK 313      // (NE+127)/128
#define NSPLIT 4

// ---- fused prep: [0,1250) x0->e16 pad ; [1250,1680) w2 -> B-frag images ; [1680..) deg=0 ----
__global__ __launch_bounds__(256) void prep_fused_kernel(
    const float* __restrict__ x, _Float16* __restrict__ e16,
    const float* __restrict__ w2a, const float* __restrict__ b2a, _Float16* __restrict__ oa,
    const float* __restrict__ w2b, const float* __restrict__ b2b, _Float16* __restrict__ ob,
    const float* __restrict__ w2c, const float* __restrict__ b2c, _Float16* __restrict__ oc,
    int* __restrict__ deg)
{
  if (blockIdx.x < 1250) {
    int idx = blockIdx.x * 256 + threadIdx.x;   // over NN*16
    int n = idx >> 4, i = idx & 15;
    e16[idx] = (i < 13) ? (_Float16)x[(size_t)n * 13 + i] : (_Float16)0.f;
    return;
  }
  if (blockIdx.x >= 1680) {
    int n = (blockIdx.x - 1680) * 256 + threadIdx.x;
    if (n < NN) deg[n] = 0;
    return;
  }
  const int TOT0 = 68 * 2 * 64, TOT1 = 132 * 4 * 64, TOT2 = 264 * 4 * 64;
  int idx = (blockIdx.x - 1250) * 256 + threadIdx.x;
  const float *w2, *b2; _Float16* op; int mi, mo, mpsh, CT;
  if (idx < TOT0) { w2 = w2a; b2 = b2a; op = oa; mi = 13; mo = 32; mpsh = 4; CT = 2; }
  else if (idx < TOT0 + TOT1) { idx -= TOT0; w2 = w2b; b2 = b2b; op = ob; mi = 32; mo = 64; mpsh = 5; CT = 4; }
  else if (idx < TOT0 + TOT1 + TOT2) { idx -= TOT0 + TOT1; w2 = w2c; b2 = b2c; op = oc; mi = 64; mo = 64; mpsh = 6; CT = 4; }
  else return;
  int l = idx & 63;
  int ct = (idx >> 6) % CT;
  int c = idx / (64 * CT);
  int q = l >> 4;
  int n = ct * 16 + (l & 15);
  int mask = (1 << mpsh) - 1;
  half8_t v;
#pragma unroll
  for (int j = 0; j < 8; ++j) {
    int r = c * 32 + q * 8 + j;
    int k = r >> mpsh, i = r & mask;
    float f = 0.f;
    if (i < mi) {
      if (k < 128) f = w2[(size_t)(k * mi + i) * mo + n];
      else if (k == 128) f = b2[(size_t)i * mo + n];
    }
    v[j] = (_Float16)f;
  }
  *(half8_t*)(op + (size_t)idx * 8) = v;
}

// ---- CSR build: histogram, parallel scan, fill ----
__global__ __launch_bounds__(256) void deg_kernel(const int* __restrict__ dst, int* __restrict__ deg) {
  int e = blockIdx.x * 256 + threadIdx.x;
  if (e < NE) atomicAdd(&deg[dst[e]], 1);
}

// 1024 threads; each owns CH=20 nodes in registers; wave shfl-scan + cross-wave scan.
__global__ __launch_bounds__(1024) void scan_kernel(
    const int* __restrict__ deg, int* __restrict__ row_ptr, int* __restrict__ cursor)
{
  constexpr int CH = 20;                 // 1024*20 = 20480 >= NN+1
  __shared__ int wsum[16];
  int t = threadIdx.x;
  int lane = t & 63, w = t >> 6;
  int base = t * CH;
  int local[CH];
#pragma unroll
  for (int i = 0; i < CH; ++i) {
    int n = base + i;
    local[i] = (n < NN) ? deg[n] : 0;
  }
  int s = 0;
#pragma unroll
  for (int i = 0; i < CH; ++i) s += local[i];
  // wave-64 inclusive scan of s
  int sc = s;
#pragma unroll
  for (int d = 1; d < 64; d <<= 1) {
    int v = __shfl_up(sc, d, 64);
    if (lane >= d) sc += v;
  }
  if (lane == 63) wsum[w] = sc;
  __syncthreads();
  if (w == 0 && lane < 16) {
    int v = wsum[lane];
    int scc = v;
#pragma unroll
    for (int d = 1; d < 16; d <<= 1) {
      int u = __shfl_up(scc, d, 64);
      if (lane >= d) scc += u;
    }
    wsum[lane] = scc - v;                // exclusive wave prefix
  }
  __syncthreads();
  int run = wsum[w] + (sc - s);          // exclusive prefix for this thread
#pragma unroll
  for (int i = 0; i < CH; ++i) {
    int n = base + i;
    if (n < NN) { row_ptr[n] = run; cursor[n] = run; run += local[i]; }
    else if (n == NN) row_ptr[NN] = run;
  }
}

__global__ __launch_bounds__(256) void fill_kernel(
    const int* __restrict__ dst, int* __restrict__ cursor, int* __restrict__ eids)
{
  int e = blockIdx.x * 256 + threadIdx.x;
  if (e < NE) { int p = atomicAdd(&cursor[dst[e]], 1); eids[p] = e; }
}

// ---------------- fused h-MLP + message GEMM, partial-store epilogue (NO atomics) ----------------
template <int MIP, int MO, int NCC, int KCNT>
__global__ __launch_bounds__(256, 4) void msg9_kernel(
    const float* __restrict__ ea, const float* __restrict__ w1,
    const float* __restrict__ b1, const _Float16* __restrict__ xe,
    const int* __restrict__ src,
    const _Float16* __restrict__ w2h, _Float16* __restrict__ msgp)
{
  constexpr int CT = MO / 16;
  constexpr int CHB = CT * 1024;
  constexpr int XLSS = MIP + 8;
  constexpr int HSTW = KCNT | 1;          // h row stride in words (odd -> conflict-free)
  constexpr int XV = (MIP == 64) ? 2 : 1;
  constexpr int NU2 = MIP / 16;
  constexpr int KH = (KCNT + 1) >> 1;
  constexpr int XB = 128 * XLSS * 2;
  constexpr int HB = 128 * HSTW * 4;
  constexpr int SBYTES = (XB > HB) ? XB : HB;

  __shared__ char sb[SBYTES];
  __shared__ uint4 wsb[2][CHB / 16];
  __shared__ float w1s[5 * 128 + 128];

  _Float16* sxb = (_Float16*)sb;
  unsigned* hls = (unsigned*)sb;

  const int t = threadIdx.x;
  const int wave = t >> 6, lane = t & 63;
  const int l15 = lane & 15, q = lane >> 4;
  const int split = blockIdx.x / NBLK;
  const int e0 = (blockIdx.x % NBLK) * 128;
  const int c0 = NCC * split;
  const int kg0 = KCNT * split;

  // ---- phase A: stage x rows (2 threads/row), w1/b1; edge attrs to regs ----
  {
    int rowA = t >> 1;
    int egA = e0 + rowA; if (egA >= NE) egA = NE - 1;
    const uint4* xr = (const uint4*)(xe + (size_t)src[egA] * MIP);
    uint4* xd = (uint4*)(sxb + rowA * XLSS);
#pragma unroll
    for (int u = 0; u < NU2; ++u) xd[(t & 1) * NU2 + u] = xr[(t & 1) * NU2 + u];
  }
  const int te = t & 127;
  float ear[5];
  {
    int ege = e0 + te; if (ege >= NE) ege = NE - 1;
#pragma unroll
    for (int j = 0; j < 5; ++j) ear[j] = ea[(size_t)ege * 5 + j];
  }
  for (int i = t; i < 768; i += 256) w1s[i] = (i < 640) ? w1[i] : b1[i - 640];
  __syncthreads();

  // ---- x fragments to registers (2 M-subtiles per wave) ----
  const int wbase = wave * 32;
  half8_t xf[2][XV];
#pragma unroll
  for (int s = 0; s < 2; ++s) {
    int el = wbase + s * 16 + l15;
    int i0 = (MIP == 16) ? (q & 1) * 8 : q * 8;
    xf[s][0] = *(const half8_t*)(sxb + el * XLSS + i0);
    if constexpr (MIP == 64)
      xf[s][XV - 1] = *(const half8_t*)(sxb + el * XLSS + 32 + q * 8);
  }
  __syncthreads();

  // ---- phase B: h rows (packed-dup uint), each edge split across thread halves ----
  {
    int kh = t >> 7;
    int klo = kh * KH;
    int khi = klo + KH; if (khi > KCNT) khi = KCNT;
    for (int kl = klo; kl < khi; ++kl) {
      int kg = kg0 + kl;
      float v;
      if (kg < 128) {
        v = w1s[640 + kg];
#pragma unroll
        for (int j = 0; j < 5; ++j) v = fmaf(ear[j], w1s[j * 128 + kg], v);
        v = fmaxf(v, 0.f);
      } else v = (kg == 128) ? 1.f : 0.f;
      union { _Float16 f; unsigned short u; } cv; cv.f = (_Float16)v;
      hls[te * HSTW + kl] = (unsigned)cv.u * 0x10001u;
    }
  }
  __syncthreads();

  // ---- K loop: 1 barrier/chunk, double-buffered LDS W, all reg indices static ----
  floatx4 acc[2][CT];
#pragma unroll
  for (int s = 0; s < 2; ++s)
#pragma unroll
    for (int b = 0; b < CT; ++b) acc[s][b] = (floatx4){0.f, 0.f, 0.f, 0.f};

  const char* wgp = (const char*)w2h + (size_t)c0 * CHB;
  uint4 r4; uint2 r2;
  if constexpr (CT == 4) r4 = *(const uint4*)(wgp + t * 16);
  else r2 = *(const uint2*)(wgp + t * 8);

#pragma unroll 2
  for (int cc = 0; cc < NCC; ++cc) {
    if constexpr (CT == 4) wsb[cc & 1][t] = r4;
    else ((uint2*)wsb[cc & 1])[t] = r2;
    __syncthreads();
    if (cc + 1 < NCC) {
      if constexpr (CT == 4) r4 = *(const uint4*)(wgp + (size_t)(cc + 1) * CHB + t * 16);
      else r2 = *(const uint2*)(wgp + (size_t)(cc + 1) * CHB + t * 8);
    }
    const _Float16* wb = (const _Float16*)wsb[cc & 1];
    half8_t bf[CT];
#pragma unroll
    for (int b = 0; b < CT; ++b)
      bf[b] = *(const half8_t*)(wb + (b * 64 + lane) * 8);
    int kl;
    if constexpr (MIP == 64) kl = cc >> 1;
    else if constexpr (MIP == 32) kl = cc;
    else kl = 2 * cc + (q >> 1);
#pragma unroll
    for (int s = 0; s < 2; ++s) {
      _Float16 hv = *(const _Float16*)(hls + (wbase + s * 16 + l15) * HSTW + kl);
      half8_t af;
      if constexpr (MIP == 64) af = xf[s][cc & 1] * hv;
      else af = xf[s][0] * hv;
#pragma unroll
      for (int b = 0; b < CT; ++b)
        acc[s][b] = __builtin_amdgcn_mfma_f32_16x16x32_f16(af, bf[b], acc[s][b], 0, 0, 0);
    }
  }

  // ---- epilogue: plain fp16 partial stores, no atomics ----
  _Float16* mp = msgp + (size_t)split * NE * MO;
#pragma unroll
  for (int s = 0; s < 2; ++s) {
    int rowb = wbase + s * 16 + q * 4;
#pragma unroll
    for (int b = 0; b < CT; ++b) {
      int n = b * 16 + l15;
#pragma unroll
      for (int r = 0; r < 4; ++r) {
        int row = rowb + r;
        int e = e0 + row;
        if (e < NE) mp[(size_t)e * MO + n] = (_Float16)acc[s][b][r];
      }
    }
  }
}

// ---- gather: per node, sum CSR-listed edge partials (+root-GEMM +bias), ELU unless FINAL ----
template <int MIN_, int XST, int MO, int FINAL>
__global__ __launch_bounds__(256) void gather_kernel(
    const _Float16* __restrict__ e16in, const float* __restrict__ root,
    const float* __restrict__ bias, const int* __restrict__ row_ptr,
    const int* __restrict__ eids, const _Float16* __restrict__ msgp,
    _Float16* __restrict__ oute, float* __restrict__ outf)
{
  constexpr int NPB = 256 / MO;
  int n = blockIdx.x * NPB + threadIdx.x / MO;
  int o = threadIdx.x % MO;
  if (n >= NN) return;
  float a = bias[o];
#pragma unroll
  for (int i = 0; i < MIN_; ++i)
    a = fmaf((float)e16in[(size_t)n * XST + i], root[i * MO + o], a);
  int r0 = row_ptr[n], r1 = row_ptr[n + 1];
  for (int j = r0; j < r1; ++j) {
    int e = eids[j];
#pragma unroll
    for (int s = 0; s < NSPLIT; ++s)
      a += (float)msgp[((size_t)s * NE + e) * MO + o];
  }
  if constexpr (FINAL) {
    outf[(size_t)n * MO + o] = a;
  } else {
    float v = a > 0.f ? a : (expf(a) - 1.f);
    oute[(size_t)n * MO + o] = (_Float16)v;
  }
}

// ---- pooling (segment mean over sorted batch, fused ELU) + 3-layer FC head ----
__global__ __launch_bounds__(64) void pool_fc_kernel(
    const float* __restrict__ xn2, const int* __restrict__ batch,
    const float* __restrict__ f1w, const float* __restrict__ f1b,
    const float* __restrict__ f2w, const float* __restrict__ f2b,
    const float* __restrict__ f3w, const float* __restrict__ f3b,
    float* __restrict__ out)
{
  __shared__ float xg[64]; __shared__ float a1[32]; __shared__ float a2[16];
  int g = blockIdx.x, t = threadIdx.x;
  int lo = 0, hi = NN;
  while (lo < hi) { int m = (lo + hi) >> 1; if (batch[m] < g) lo = m + 1; else hi = m; }
  int start = lo; hi = NN;
  while (lo < hi) { int m = (lo + hi) >> 1; if (batch[m] <= g) lo = m + 1; else hi = m; }
  int end = lo;
  float acc = 0.f;
  for (int n = start; n < end; ++n) {
    float v = xn2[(size_t)n * 64 + t];
    acc += v > 0.f ? v : (expf(v) - 1.f);
  }
  float c = (end > start) ? (float)(end - start) : 1.f;
  xg[t] = acc / c;
  __syncthreads();
  if (t < 32) {
    float a = f1b[t];
    for (int i = 0; i < 64; ++i) a = fmaf(xg[i], f1w[i * 32 + t], a);
    a1[t] = a > 0.f ? a : (expf(a) - 1.f);
  }
  __syncthreads();
  if (t < 16) {
    float a = f2b[t];
    for (int i = 0; i < 32; ++i) a = fmaf(a1[i], f2w[i * 16 + t], a);
    a2[t] = a > 0.f ? a : (expf(a) - 1.f);
  }
  __syncthreads();
  if (t == 0) {
    float a = f3b[0];
    for (int i = 0; i < 16; ++i) a = fmaf(a2[i], f3w[i], a);
    out[g] = a;
  }
}

extern "C" void kernel_launch(void* const* d_in, const int* in_sizes, int n_in,
                              void* d_out, int out_size, void* d_ws, size_t ws_size,
                              hipStream_t stream)
{
  const float* x_in  = (const float*)d_in[0];
  const int*   ei    = (const int*)d_in[1];
  const float* ea    = (const float*)d_in[2];
  const int*   batch = (const int*)d_in[3];
  const float* W1[3] = {(const float*)d_in[4],  (const float*)d_in[10], (const float*)d_in[16]};
  const float* B1[3] = {(const float*)d_in[5],  (const float*)d_in[11], (const float*)d_in[17]};
  const float* W2[3] = {(const float*)d_in[6],  (const float*)d_in[12], (const float*)d_in[18]};
  const float* B2[3] = {(const float*)d_in[7],  (const float*)d_in[13], (const float*)d_in[19]};
  const float* RT[3] = {(const float*)d_in[8],  (const float*)d_in[14], (const float*)d_in[20]};
  const float* BS[3] = {(const float*)d_in[9],  (const float*)d_in[15], (const float*)d_in[21]};
  const float* f1w = (const float*)d_in[22]; const float* f1b = (const float*)d_in[23];
  const float* f2w = (const float*)d_in[24]; const float* f2b = (const float*)d_in[25];
  const float* f3w = (const float*)d_in[26]; const float* f3b = (const float*)d_in[27];

  char* ws = (char*)d_ws;
  size_t off = 0;
  auto alloc = [&](size_t bytes) { void* p = ws + off; off += (bytes + 255) & ~(size_t)255; return p; };
  float*    xn2   = (float*)alloc((size_t)NN * 64 * 4);
  _Float16* e16_0 = (_Float16*)alloc((size_t)NN * 16 * 2);
  _Float16* e16_1 = (_Float16*)alloc((size_t)NN * 32 * 2);
  _Float16* e16_2 = (_Float16*)alloc((size_t)NN * 64 * 2);
  _Float16* w2h0  = (_Float16*)alloc((size_t)68 * 2048);
  _Float16* w2h1  = (_Float16*)alloc((size_t)132 * 4096);
  _Float16* w2h2  = (_Float16*)alloc((size_t)264 * 4096);
  _Float16* msgp  = (_Float16*)alloc((size_t)NSPLIT * NE * 64 * 2);
  int*      deg     = (int*)alloc((size_t)NN * 4);
  int*      row_ptr = (int*)alloc((size_t)(NN + 1) * 4);
  int*      cursor  = (int*)alloc((size_t)NN * 4);
  int*      eids    = (int*)alloc((size_t)NE * 4);

  const int* srcp = ei;
  const int* dstp = ei + NE;

  prep_fused_kernel<<<1680 + (NN + 255) / 256, 256, 0, stream>>>(
      x_in, e16_0, W2[0], B2[0], w2h0, W2[1], B2[1], w2h1, W2[2], B2[2], w2h2, deg);
  deg_kernel<<<(NE + 255) / 256, 256, 0, stream>>>(dstp, deg);
  scan_kernel<<<1, 1024, 0, stream>>>(deg, row_ptr, cursor);
  fill_kernel<<<(NE + 255) / 256, 256, 0, stream>>>(dstp, cursor, eids);

  // ---- layer 0 ----
  msg9_kernel<16, 32, 17, 34><<<NBLK * NSPLIT, 256, 0, stream>>>(
      ea, W1[0], B1[0], e16_0, srcp, w2h0, msgp);
  gather_kernel<13, 16, 32, 0><<<(NN + 7) / 8, 256, 0, stream>>>(
      e16_0, RT[0], BS[0], row_ptr, eids, msgp, e16_1, xn2);

  // ---- layer 1 ----
  msg9_kernel<32, 64, 33, 33><<<NBLK * NSPLIT, 256, 0, stream>>>(
      ea, W1[1], B1[1], e16_1, srcp, w2h1, msgp);
  gather_kernel<32, 32, 64, 0><<<(NN + 3) / 4, 256, 0, stream>>>(
      e16_1, RT[1], BS[1], row_ptr, eids, msgp, e16_2, xn2);

  // ---- layer 2 ----
  msg9_kernel<64, 64, 66, 33><<<NBLK * NSPLIT, 256, 0, stream>>>(
      ea, W1[2], B1[2], e16_2, srcp, w2h2, msgp);
  gather_kernel<64, 64, 64, 1><<<(NN + 3) / 4, 256, 0, stream>>>(
      e16_2, RT[2], BS[2], row_ptr, eids, msgp, e16_2, xn2);

  pool_fc_kernel<<<NG, 64, 0, stream>>>(xn2, batch, f1w, f1b, f2w, f2b, f3w, f3b, (float*)d_out);
}